// Round 16
// baseline (12901.089 us; speedup 1.0000x reference)
//
#include <hip/hip_runtime.h>
#include <hip/hip_bf16.h>

typedef float f32x4 __attribute__((ext_vector_type(4)));
typedef __bf16 bf16x8 __attribute__((ext_vector_type(8)));

#define B_SZ 2048
#define T_IN 48
#define FEAT 64
#define UNITS 1024
#define GCOLS 4096   // 4*UNITS
#define OUT_STEPS 64
#define KWARM 1088   // UNITS + FEAT
#define NSTEP (T_IN + OUT_STEPS)
#define NBLK 256

// Gate-major column permutation: c' = 64*Bk + 16*g + u
__device__ __forceinline__ int oc_of(int c) {
    return (((c >> 4) & 3) * UNITS) + ((c >> 6) * 16) + (c & 15);
}

typedef __attribute__((address_space(1))) const void gas_t;
typedef __attribute__((address_space(3))) void las_t;

__device__ __forceinline__ void gl_lds16(const void* g, void* l) {
    __builtin_amdgcn_global_load_lds((gas_t*)g, (las_t*)l, 16, 0, 0);
}
__device__ __forceinline__ float sigm(float x) {
    return __builtin_amdgcn_rcpf(1.0f + __expf(-x));
}
__device__ __forceinline__ float tanh_fast(float x) {
    float e = __expf(2.0f * x);
    return 1.0f - 2.0f * __builtin_amdgcn_rcpf(e + 1.0f);
}

// Deadlock-proof grid barrier. 256 blocks vs 512 resident slots (2x margin).
// Arrival: one device-scope atomicAdd per block. Poll: relaxed agent-scope
// atomic LOAD (no RMW storm). Timeout: poison the counter (+1<<20 exceeds all
// targets <= 256*112) so every block passes all remaining barriers instantly
// -> kernel ALWAYS terminates; deadlock shows as fast absmax failure.
__device__ __forceinline__ int grid_barrier(int* cnt, int target) {
    __threadfence();                 // release: h/pred stores visible device-wide
    __syncthreads();
    __shared__ int ok_s;
    if (threadIdx.x == 0) {
        atomicAdd(cnt, 1);
        int ok = 1, spins = 0;
        while (__hip_atomic_load(cnt, __ATOMIC_RELAXED, __HIP_MEMORY_SCOPE_AGENT) < target) {
            __builtin_amdgcn_s_sleep(4);
            if (++spins > (1 << 21)) { ok = 0; atomicAdd(cnt, 1 << 20); break; }
        }
        ok_s = ok;
    }
    __syncthreads();
    __threadfence();                 // acquire: invalidate stale cached h
    return ok_s;
}

// ---------- precompute kernels (unchanged, correctness-proven) ----------

__global__ __launch_bounds__(256) void reorder_UW(const float* __restrict__ U, const float* __restrict__ W,
                                                  __hip_bfloat16* __restrict__ UTw) {
    __shared__ __hip_bfloat16 t[64][64];
    const int k0 = blockIdx.x * 64;   // 17 tiles
    const int c0 = blockIdx.y * 64;   // 64 tiles
    const int tid = threadIdx.x;
#pragma unroll
    for (int i = 0; i < 16; ++i) {
        int idx = tid + i * 256;
        int rk = idx >> 6, cc = idx & 63;
        int k = k0 + rk, c = c0 + cc;
        int oc = oc_of(c);
        float v = (k < UNITS) ? U[(size_t)k * GCOLS + oc] : W[(size_t)(k - UNITS) * GCOLS + oc];
        t[rk][cc] = __float2bfloat16(v);
    }
    __syncthreads();
#pragma unroll
    for (int i = 0; i < 16; ++i) {
        int idx = tid + i * 256;
        int rc = idx >> 6, kk = idx & 63;
        UTw[(size_t)(c0 + rc) * KWARM + k0 + kk] = t[kk][rc];
    }
}

__global__ __launch_bounds__(256) void transpose_Wd(const float* __restrict__ Wd, __hip_bfloat16* __restrict__ WdT) {
    __shared__ __hip_bfloat16 t[64][64];
    const int k0 = blockIdx.x * 64;  // 16 blocks
    const int tid = threadIdx.x;
#pragma unroll
    for (int i = 0; i < 16; ++i) {
        int idx = tid + i * 256;
        int rk = idx >> 6, ff = idx & 63;
        t[rk][ff] = __float2bfloat16(Wd[(size_t)(k0 + rk) * FEAT + ff]);
    }
    __syncthreads();
#pragma unroll
    for (int i = 0; i < 16; ++i) {
        int idx = tid + i * 256;
        int rf = idx >> 6, kk = idx & 63;
        WdT[(size_t)rf * UNITS + k0 + kk] = t[kk][rf];
    }
}

__global__ __launch_bounds__(256) void build_UTdec(const __hip_bfloat16* __restrict__ UTw,
                                                   const __hip_bfloat16* __restrict__ WdT,
                                                   __hip_bfloat16* __restrict__ UTd) {
    __shared__ float Wl[64][16];
    const int k = blockIdx.x * 256 + threadIdx.x;  // 4 blocks
    const int c0 = blockIdx.y * 16;                // 256 blocks
    const int tid = threadIdx.x;
#pragma unroll
    for (int i = 0; i < 4; ++i) {
        int idx = tid + i * 256;
        int f = idx >> 4, cc = idx & 15;
        Wl[f][cc] = __bfloat162float(UTw[(size_t)(c0 + cc) * KWARM + UNITS + f]);
    }
    __syncthreads();
    float acc[16];
#pragma unroll
    for (int cc = 0; cc < 16; ++cc) acc[cc] = 0.f;
    for (int f = 0; f < 64; ++f) {
        float wd = __bfloat162float(WdT[(size_t)f * UNITS + k]);
#pragma unroll
        for (int cc = 0; cc < 16; ++cc) acc[cc] += wd * Wl[f][cc];
    }
#pragma unroll
    for (int cc = 0; cc < 16; ++cc) {
        float uv = __bfloat162float(UTw[(size_t)(c0 + cc) * KWARM + k]);
        UTd[(size_t)(c0 + cc) * UNITS + k] = __float2bfloat16(uv + acc[cc]);
    }
}

__global__ __launch_bounds__(256) void build_bias(const float* __restrict__ b, const float* __restrict__ bd,
                                                  const __hip_bfloat16* __restrict__ UTw,
                                                  float* __restrict__ bw, float* __restrict__ bdc) {
    const int c = blockIdx.x * 256 + threadIdx.x;  // 16 blocks
    const int oc = oc_of(c);
    float base = b[oc];
    float s = 0.f;
    for (int f = 0; f < FEAT; ++f) s += bd[f] * __bfloat162float(UTw[(size_t)c * KWARM + UNITS + f]);
    bw[c] = base;
    bdc[c] = base + s;
}

__global__ void convert_x(const float* __restrict__ x, __hip_bfloat16* __restrict__ xb, int n) {
    int i = blockIdx.x * blockDim.x + threadIdx.x;
    if (i < n) xb[i] = __float2bfloat16(x[i]);
}

// ---------- persistent fused LSTM: all 112 steps, one regular launch ----------
// R16: 256 blocks (2x co-residency margin vs R15's exact-fit 512 which hung),
// each block runs TWO n-tiles (nb=j, j+16) per step with the proven R12 tile
// structure. c-state in registers (cvA/cvB). Deadlock-proof poisoning barrier.
__global__ __launch_bounds__(256) void lstm_persistent(
    __hip_bfloat16* __restrict__ hA,                 // [2048][1024] zeroed
    __hip_bfloat16* __restrict__ hB,                 // [2048][1024]
    const __hip_bfloat16* __restrict__ xbf,          // [2048][48][64]
    const __hip_bfloat16* __restrict__ UTw,          // [4096][1088]
    const __hip_bfloat16* __restrict__ UTd,          // [4096][1024]
    const float* __restrict__ bw,                    // [4096]
    const float* __restrict__ bdc,                   // [4096]
    const __hip_bfloat16* __restrict__ WdT,          // [64][1024]
    const float* __restrict__ bd,                    // [64]
    float* __restrict__ out,                         // [2048][64][64]
    int* __restrict__ sync_cnt)                      // zeroed each call
{
    constexpr int NKT_W = KWARM / 64;   // 17
    constexpr int NKT_D = UNITS / 64;   // 16
    constexpr size_t OFFW = (size_t)2048 * KWARM * 2;   // +16 nb-slices in UTw
    constexpr size_t OFFD = (size_t)2048 * UNITS * 2;   // +16 nb-slices in UTd

    __shared__ alignas(16) __hip_bfloat16 Al[2 * 8192];   // 32 KB
    __shared__ alignas(16) __hip_bfloat16 Bl[2 * 8192];   // 32 KB

    const int tid = threadIdx.x;
    const int lane = tid & 63;
    const int wv = tid >> 6;
    const int wr = wv >> 1, wc = wv & 1;
    const int p = blockIdx.x;          // 256 blocks
    const int mb = p >> 4;             // 0..15
    const int j = p & 15;              // 0..15 ; tiles nb = j and j+16
    const int m0 = mb * 128;
    const bool predBlk = (j < 4);

    const int lrow = lane >> 3;
    const int scol = ((lane & 7) * 16) ^ (lrow << 4);   // swizzled source byte col

    // loop-invariant offsets/bases (tile-1 B bases = tile-0 + OFFW/OFFD)
    size_t aOff[4]; const char* xB[4]; const char* bWb[4]; const char* bDb[4];
#pragma unroll
    for (int r = 0; r < 4; ++r) {
        int row = (r * 4 + wv) * 8 + lrow;
        aOff[r] = (size_t)(m0 + row) * (UNITS * 2) + scol;
        xB[r] = (const char*)xbf + (size_t)(m0 + row) * (T_IN * FEAT * 2) + scol;
        bWb[r] = (const char*)UTw + (size_t)(j * 128 + row) * (KWARM * 2) + scol;
        bDb[r] = (const char*)UTd + (size_t)(j * 128 + row) * (UNITS * 2) + scol;
    }

    const int ar = lane & 15;
    const int ko = (lane >> 4) << 3;
    const int swz = (ar & 7) << 3;

    const char* wBp = (const char*)WdT + ((size_t)(16 * j + ar) * UNITS + ko) * 2;

    // epilogue geometry + biases (registers for the whole run)
    const int u16 = lane & 15;
    const int unit0 = (j * 2 + wc) * 16 + u16;          // tile 1: +512
    const int rbase = m0 + 64 * wr + ((lane >> 4) << 2);
    float bvw[2][4], bvd[2][4];
#pragma unroll
    for (int t = 0; t < 2; ++t) {
        const int n0t = (j + 16 * t) * 128;
#pragma unroll
        for (int g = 0; g < 4; ++g) {
            bvw[t][g] = bw[n0t + 64 * wc + 16 * g + u16];
            bvd[t][g] = bdc[n0t + 64 * wc + 16 * g + u16];
        }
    }
    const float bdv = predBlk ? bd[16 * j + u16] : 0.f;

    // c-state in registers for both tiles
    float cvA[16] = {}, cvB[16] = {};

    int healthy = 1;

#pragma unroll 1
    for (int step = 0; step < NSTEP; ++step) {
        const bool warm = step < T_IN;
        const char* hin = (const char*)((step & 1) ? hB : hA);
        __hip_bfloat16* hOut = (step & 1) ? hA : hB;

        const char* aS[4];
#pragma unroll
        for (int r = 0; r < 4; ++r) aS[r] = hin + aOff[r];

        // ---- one 128x128 tile: K-loop + gate epilogue ----
        auto warm_tile = [&](size_t bOff, float* cvt, const float* bvt, int unitT) {
            f32x4 acc[4][4] = {};
            auto stage = [&](int kt) {
                const int buf = kt & 1;
#pragma unroll
                for (int r = 0; r < 4; ++r) {
                    const char* s = (kt == NKT_W - 1) ? (xB[r] + step * (FEAT * 2)) : (aS[r] + kt * 128);
                    gl_lds16(s, (char*)Al + buf * 16384 + (r * 4 + wv) * 1024);
                }
#pragma unroll
                for (int r = 0; r < 4; ++r)
                    gl_lds16(bWb[r] + bOff + kt * 128, (char*)Bl + buf * 16384 + (r * 4 + wv) * 1024);
            };
            auto compute = [&](int kt) {
                const int buf = kt & 1;
#pragma unroll
                for (int kk = 0; kk < 2; ++kk) {
                    bf16x8 af[4], bfr[4];
#pragma unroll
                    for (int mi = 0; mi < 4; ++mi)
                        af[mi] = *reinterpret_cast<const bf16x8*>(&Al[buf * 8192 + (64 * wr + 16 * mi + ar) * 64 + ((32 * kk + ko) ^ swz)]);
#pragma unroll
                    for (int ni = 0; ni < 4; ++ni)
                        bfr[ni] = *reinterpret_cast<const bf16x8*>(&Bl[buf * 8192 + (64 * wc + 16 * ni + ar) * 64 + ((32 * kk + ko) ^ swz)]);
#pragma unroll
                    for (int mi = 0; mi < 4; ++mi)
#pragma unroll
                        for (int ni = 0; ni < 4; ++ni)
                            acc[mi][ni] = __builtin_amdgcn_mfma_f32_16x16x32_bf16(af[mi], bfr[ni], acc[mi][ni], 0, 0, 0);
                }
            };
            stage(0);
#pragma unroll
            for (int kt = 0; kt < NKT_W - 1; ++kt) {
                stage(kt + 1);
                asm volatile("s_waitcnt vmcnt(8) lgkmcnt(0)" ::: "memory");
                __builtin_amdgcn_s_barrier();
                compute(kt);
                __builtin_amdgcn_s_barrier();
            }
            asm volatile("s_waitcnt vmcnt(0) lgkmcnt(0)" ::: "memory");
            __builtin_amdgcn_s_barrier();
            compute(NKT_W - 1);
#pragma unroll
            for (int mi = 0; mi < 4; ++mi)
#pragma unroll
                for (int reg = 0; reg < 4; ++reg) {
                    float zi = acc[mi][0][reg] + bvt[0];
                    float zf = acc[mi][1][reg] + bvt[1];
                    float zg = acc[mi][2][reg] + bvt[2];
                    float zo = acc[mi][3][reg] + bvt[3];
                    float cn = sigm(zf) * cvt[mi * 4 + reg] + sigm(zi) * tanh_fast(zg);
                    cvt[mi * 4 + reg] = cn;
                    hOut[(size_t)(rbase + 16 * mi + reg) * UNITS + unitT] =
                        __float2bfloat16(sigm(zo) * tanh_fast(cn));
                }
        };

        auto dec_tile = [&](size_t bOff, float* cvt, const float* bvt, int unitT, bool predT, int tstep) {
            f32x4 acc[4][4] = {};
            f32x4 accp[2] = {};
            bf16x8 Wf[2][2];
            auto stage = [&](int kt) {
                const int buf = kt & 1;
#pragma unroll
                for (int r = 0; r < 4; ++r)
                    gl_lds16(aS[r] + kt * 128, (char*)Al + buf * 16384 + (r * 4 + wv) * 1024);
#pragma unroll
                for (int r = 0; r < 4; ++r)
                    gl_lds16(bDb[r] + bOff + kt * 128, (char*)Bl + buf * 16384 + (r * 4 + wv) * 1024);
            };
            auto loadWf = [&](int kt) {
                if (predT) {
#pragma unroll
                    for (int kk = 0; kk < 2; ++kk)
                        Wf[kt & 1][kk] = *reinterpret_cast<const bf16x8*>(wBp + kt * 128 + kk * 64);
                }
            };
            auto compute = [&](int kt) {
                const int buf = kt & 1;
#pragma unroll
                for (int kk = 0; kk < 2; ++kk) {
                    bf16x8 af[4], bfr[4];
#pragma unroll
                    for (int mi = 0; mi < 4; ++mi)
                        af[mi] = *reinterpret_cast<const bf16x8*>(&Al[buf * 8192 + (64 * wr + 16 * mi + ar) * 64 + ((32 * kk + ko) ^ swz)]);
#pragma unroll
                    for (int ni = 0; ni < 4; ++ni)
                        bfr[ni] = *reinterpret_cast<const bf16x8*>(&Bl[buf * 8192 + (64 * wc + 16 * ni + ar) * 64 + ((32 * kk + ko) ^ swz)]);
#pragma unroll
                    for (int mi = 0; mi < 4; ++mi)
#pragma unroll
                        for (int ni = 0; ni < 4; ++ni)
                            acc[mi][ni] = __builtin_amdgcn_mfma_f32_16x16x32_bf16(af[mi], bfr[ni], acc[mi][ni], 0, 0, 0);
                    if (predT) {
#pragma unroll
                        for (int pi = 0; pi < 2; ++pi)
                            accp[pi] = __builtin_amdgcn_mfma_f32_16x16x32_bf16(af[2 * wc + pi], Wf[kt & 1][kk], accp[pi], 0, 0, 0);
                    }
                }
            };
            stage(0);
            loadWf(0);
#pragma unroll
            for (int kt = 0; kt < NKT_D - 1; ++kt) {
                stage(kt + 1);
                loadWf(kt + 1);
                if (predT) asm volatile("s_waitcnt vmcnt(10) lgkmcnt(0)" ::: "memory");
                else       asm volatile("s_waitcnt vmcnt(8) lgkmcnt(0)" ::: "memory");
                __builtin_amdgcn_s_barrier();
                compute(kt);
                __builtin_amdgcn_s_barrier();
            }
            asm volatile("s_waitcnt vmcnt(0) lgkmcnt(0)" ::: "memory");
            __builtin_amdgcn_s_barrier();
            compute(NKT_D - 1);
#pragma unroll
            for (int mi = 0; mi < 4; ++mi)
#pragma unroll
                for (int reg = 0; reg < 4; ++reg) {
                    float zi = acc[mi][0][reg] + bvt[0];
                    float zf = acc[mi][1][reg] + bvt[1];
                    float zg = acc[mi][2][reg] + bvt[2];
                    float zo = acc[mi][3][reg] + bvt[3];
                    float cn = sigm(zf) * cvt[mi * 4 + reg] + sigm(zi) * tanh_fast(zg);
                    cvt[mi * 4 + reg] = cn;
                    hOut[(size_t)(rbase + 16 * mi + reg) * UNITS + unitT] =
                        __float2bfloat16(sigm(zo) * tanh_fast(cn));
                }
            if (predT) {
#pragma unroll
                for (int pi = 0; pi < 2; ++pi) {
                    const int prow = m0 + 64 * wr + 32 * wc + 16 * pi + ((lane >> 4) << 2);
                    f32x4 v = accp[pi];
#pragma unroll
                    for (int reg = 0; reg < 4; ++reg)
                        out[(size_t)(prow + reg) * (OUT_STEPS * FEAT) + (size_t)tstep * FEAT + (16 * j + u16)] = v[reg] + bdv;
                }
            }
        };

        if (warm) {
            warm_tile(0, cvA, bvw[0], unit0);
            __builtin_amdgcn_s_barrier();           // LDS WAR between tiles
            warm_tile(OFFW, cvB, bvw[1], unit0 + 512);
        } else {
            dec_tile(0, cvA, bvd[0], unit0, predBlk, step - T_IN);
            __builtin_amdgcn_s_barrier();           // LDS WAR between tiles
            dec_tile(OFFD, cvB, bvd[1], unit0 + 512, false, 0);
        }

        if (step < NSTEP - 1 && healthy)
            healthy = grid_barrier(sync_cnt, NBLK * (step + 1));
    }
}

// ---------- host ----------
extern "C" void kernel_launch(void* const* d_in, const int* in_sizes, int n_in,
                              void* d_out, int out_size, void* d_ws, size_t ws_size,
                              hipStream_t stream) {
    const float* inputs = (const float*)d_in[0];
    const float* W  = (const float*)d_in[1];
    const float* U  = (const float*)d_in[2];
    const float* b  = (const float*)d_in[3];
    const float* Wd = (const float*)d_in[4];
    const float* bd = (const float*)d_in[5];
    float* out = (float*)d_out;

    char* ws = (char*)d_ws;
    size_t off = 0;
    auto alloc = [&](size_t bytes) { char* p = ws + off; off = (off + bytes + 255) & ~255ULL; return p; };
    __hip_bfloat16* UTw = (__hip_bfloat16*)alloc((size_t)GCOLS * KWARM * 2);
    __hip_bfloat16* UTd = (__hip_bfloat16*)alloc((size_t)GCOLS * UNITS * 2);
    __hip_bfloat16* WdT = (__hip_bfloat16*)alloc((size_t)FEAT * UNITS * 2);
    __hip_bfloat16* Xbf = (__hip_bfloat16*)alloc((size_t)B_SZ * T_IN * FEAT * 2);
    __hip_bfloat16* hA  = (__hip_bfloat16*)alloc((size_t)B_SZ * UNITS * 2);
    __hip_bfloat16* hB  = (__hip_bfloat16*)alloc((size_t)B_SZ * UNITS * 2);
    float* bw  = (float*)alloc(GCOLS * 4);
    float* bdc = (float*)alloc(GCOLS * 4);
    int* sync_cnt = (int*)alloc(256);

    hipMemsetAsync(hA, 0, (size_t)B_SZ * UNITS * 2, stream);
    hipMemsetAsync(sync_cnt, 0, 256, stream);

    dim3 blk(256);
    reorder_UW<<<dim3(17, 64), blk, 0, stream>>>(U, W, UTw);
    transpose_Wd<<<dim3(16), blk, 0, stream>>>(Wd, WdT);
    build_UTdec<<<dim3(4, 256), blk, 0, stream>>>(UTw, WdT, UTd);
    build_bias<<<dim3(16), blk, 0, stream>>>(b, bd, UTw, bw, bdc);
    {
        int n = B_SZ * T_IN * FEAT;
        convert_x<<<dim3((n + 255) / 256), blk, 0, stream>>>(inputs, Xbf, n);
    }

    lstm_persistent<<<dim3(NBLK), blk, 0, stream>>>(hA, hB, Xbf, UTw, UTd,
                                                    bw, bdc, WdT, bd, out, sync_cnt);
}